// Round 3
// baseline (788.353 us; speedup 1.0000x reference)
//
#include <hip/hip_runtime.h>
#include <math.h>

#define NN 500000
#define NE 5000000
#define K_B 1954          // dst buckets of 256 nodes: ceil(500000/256)
#define NBP 500           // partition pass blocks
#define EPB 10000         // edges per partition block (NBP*EPB == NE)
#define M_SCAN (K_B * NBP)        // 977000 (bucket-major, block-minor)
#define SC_CH 4096                // scan chunk: 256 thr * 16
#define NB_SC 239                 // ceil(M_SCAN / SC_CH)
#define M_PAD (NB_SC * SC_CH)     // 978944

// ================= radix partition (no global atomics) =================

__global__ __launch_bounds__(256) void pass1_count(
    const int* __restrict__ ei, int* __restrict__ counts)
{
    __shared__ int lh[K_B];
    for (int i = threadIdx.x; i < K_B; i += 256) lh[i] = 0;
    __syncthreads();
    int e0 = blockIdx.x * EPB;
    for (int k = threadIdx.x; k < EPB; k += 256) {
        int d = ei[NE + e0 + k];
        atomicAdd(&lh[d >> 8], 1);
    }
    __syncthreads();
    for (int i = threadIdx.x; i < K_B; i += 256)
        counts[i * NBP + blockIdx.x] = lh[i];
}

__global__ __launch_bounds__(256) void scan_reduce(
    const int* __restrict__ a, int* __restrict__ partial)
{
    __shared__ int sm[256];
    int base = blockIdx.x * SC_CH + threadIdx.x * 16;
    int s = 0;
#pragma unroll
    for (int k = 0; k < 16; ++k) s += a[base + k];
    sm[threadIdx.x] = s;
    __syncthreads();
    for (int off = 128; off > 0; off >>= 1) {
        if (threadIdx.x < off) sm[threadIdx.x] += sm[threadIdx.x + off];
        __syncthreads();
    }
    if (threadIdx.x == 0) partial[blockIdx.x] = sm[0];
}

__global__ __launch_bounds__(256) void scan_mid(int* __restrict__ partial)
{
    __shared__ int sm[256];
    int t = threadIdx.x;
    int orig = (t < NB_SC) ? partial[t] : 0;
    sm[t] = orig;
    __syncthreads();
    for (int off = 1; off < 256; off <<= 1) {
        int v = (t >= off) ? sm[t - off] : 0;
        __syncthreads();
        sm[t] += v;
        __syncthreads();
    }
    if (t < NB_SC) partial[t] = sm[t] - orig;   // exclusive
}

__global__ __launch_bounds__(256) void scan_apply(
    int* __restrict__ a, const int* __restrict__ partial)
{
    __shared__ int sm[256];
    int b = blockIdx.x, t = threadIdx.x;
    int base = b * SC_CH + t * 16;
    int v[16]; int s = 0;
#pragma unroll
    for (int k = 0; k < 16; ++k) { v[k] = a[base + k]; s += v[k]; }
    sm[t] = s;
    __syncthreads();
    int orig = s;
    for (int off = 1; off < 256; off <<= 1) {
        int u = (t >= off) ? sm[t - off] : 0;
        __syncthreads();
        sm[t] += u;
        __syncthreads();
    }
    int run = partial[b] + sm[t] - orig;
#pragma unroll
    for (int k = 0; k < 16; ++k) { a[base + k] = run; run += v[k]; }
}

__global__ __launch_bounds__(256) void pass2_scatter(
    const int* __restrict__ ei, const int* __restrict__ counts,
    unsigned int* __restrict__ sorted)
{
    __shared__ int cur[K_B];
    for (int i = threadIdx.x; i < K_B; i += 256)
        cur[i] = counts[i * NBP + blockIdx.x];
    __syncthreads();
    int e0 = blockIdx.x * EPB;
    for (int k = threadIdx.x; k < EPB; k += 256) {
        int e = e0 + k;
        int s = ei[e];
        int d = ei[NE + e];
        int bin = d >> 8;
        int pos = atomicAdd(&cur[bin], 1);   // LDS atomic
        sorted[pos] = ((unsigned)(d & 255) << 20) | (unsigned)s;
    }
}

// ================= layer kernels: one block per 256-node bucket =================

__global__ __launch_bounds__(256) void proj1(
    const float* __restrict__ x, const float* __restrict__ w,
    const float* __restrict__ b, float4* __restrict__ h1)
{
    int i = blockIdx.x * 256 + threadIdx.x;
    if (i >= NN) return;
    float x0 = x[i*3+0], x1 = x[i*3+1], x2 = x[i*3+2];
    float4 o;
    float* ov = &o.x;
#pragma unroll
    for (int j = 0; j < 3; ++j) {
        float v = fmaf(x0, w[0*3+j], fmaf(x1, w[1*3+j], fmaf(x2, w[2*3+j], b[j])));
        ov[j] = v > 0.f ? v : 0.f;
    }
    o.w = 0.f;
    h1[i] = o;
}

// layer1 aggregate + combine, epilogue also applies p2 projection -> writes x2 AND h2
__global__ __launch_bounds__(256) void layer1_kernel(
    const int* __restrict__ counts, const unsigned int* __restrict__ sorted,
    const float4* __restrict__ h1, const float* __restrict__ x,
    const float* __restrict__ l1w, const float* __restrict__ l1b,
    const float* __restrict__ r1w,
    const float* __restrict__ p2w, const float* __restrict__ p2b,
    float* __restrict__ X2, float* __restrict__ H2)
{
    __shared__ float acc[256][4];
    __shared__ float slw[48], srw[48], slb[16], sp2w[256], sp2b[16];
    int t = threadIdx.x, b = blockIdx.x;
    sp2w[t] = p2w[t];
    if (t < 48) { slw[t] = l1w[t]; srw[t] = r1w[t]; }
    if (t < 16) { slb[t] = l1b[t]; sp2b[t] = p2b[t]; }
    acc[t][0] = 0.f; acc[t][1] = 0.f; acc[t][2] = 0.f; acc[t][3] = 0.f;
    __syncthreads();
    int beg = counts[b * NBP];
    int end = (b == K_B - 1) ? NE : counts[(b + 1) * NBP];
    for (int e = beg + t; e < end; e += 256) {
        unsigned v = sorted[e];
        int s = v & 0xFFFFF;
        int dlo = v >> 20;
        float4 hv = h1[s];
        atomicAdd(&acc[dlo][0], hv.x);
        atomicAdd(&acc[dlo][1], hv.y);
        atomicAdd(&acc[dlo][2], hv.z);
    }
    __syncthreads();
    int node = (b << 8) + t;
    if (node >= NN) return;
    float a0 = acc[t][0], a1 = acc[t][1], a2 = acc[t][2];
    float x0 = x[node*3+0], x1 = x[node*3+1], x2v = x[node*3+2];
    float h[16];
#pragma unroll
    for (int j = 0; j < 16; ++j) {
        float v = slb[j];
        v = fmaf(a0, slw[j], fmaf(a1, slw[16+j], fmaf(a2, slw[32+j], v)));
        v = fmaf(x0, srw[j], fmaf(x1, srw[16+j], fmaf(x2v, srw[32+j], v)));
        h[j] = v > 0.f ? v : 0.f;
    }
    float4* xp = reinterpret_cast<float4*>(X2 + (size_t)node * 16);
#pragma unroll
    for (int q = 0; q < 4; ++q)
        xp[q] = make_float4(h[q*4+0], h[q*4+1], h[q*4+2], h[q*4+3]);
    float h2[16];
#pragma unroll
    for (int j = 0; j < 16; ++j) {
        float v = sp2b[j];
#pragma unroll
        for (int k = 0; k < 16; ++k) v = fmaf(h[k], sp2w[k*16+j], v);
        h2[j] = v > 0.f ? v : 0.f;
    }
    float4* hp = reinterpret_cast<float4*>(H2 + (size_t)node * 16);
#pragma unroll
    for (int q = 0; q < 4; ++q)
        hp[q] = make_float4(h2[q*4+0], h2[q*4+1], h2[q*4+2], h2[q*4+3]);
}

// layer2 aggregate + combine; epilogue writes x3 (in place over x2) and g = l3w . relu(p3(x3))
__global__ __launch_bounds__(256) void layer2_kernel(
    const int* __restrict__ counts, const unsigned int* __restrict__ sorted,
    const float* __restrict__ H2, float* X /* x2 in, x3 out */,
    const float* __restrict__ l2w, const float* __restrict__ l2b,
    const float* __restrict__ r2w,
    const float* __restrict__ p3w, const float* __restrict__ p3b,
    const float* __restrict__ l3w, float* __restrict__ g)
{
    __shared__ float acc[256][17];
    __shared__ float slw[256], srw[256], sp3w[256];
    __shared__ float slb[16], sp3b[16], sl3w[16];
    int t = threadIdx.x, b = blockIdx.x;
    slw[t] = l2w[t]; srw[t] = r2w[t]; sp3w[t] = p3w[t];
    if (t < 16) { slb[t] = l2b[t]; sp3b[t] = p3b[t]; sl3w[t] = l3w[t]; }
#pragma unroll
    for (int k = 0; k < 17; ++k) acc[t][k] = 0.f;
    __syncthreads();
    int beg = counts[b * NBP];
    int end = (b == K_B - 1) ? NE : counts[(b + 1) * NBP];
    int q = t & 3;
    for (int e = beg + (t >> 2); e < end; e += 64) {
        unsigned v = sorted[e];
        int s = v & 0xFFFFF;
        int dlo = v >> 20;
        float4 hv = *reinterpret_cast<const float4*>(H2 + (size_t)s * 16 + q * 4);
        atomicAdd(&acc[dlo][q*4+0], hv.x);
        atomicAdd(&acc[dlo][q*4+1], hv.y);
        atomicAdd(&acc[dlo][q*4+2], hv.z);
        atomicAdd(&acc[dlo][q*4+3], hv.w);
    }
    __syncthreads();
    int node = (b << 8) + t;
    if (node >= NN) return;
    float av[16], xv[16];
#pragma unroll
    for (int k = 0; k < 16; ++k) av[k] = acc[t][k];
    const float4* xp = reinterpret_cast<const float4*>(X + (size_t)node * 16);
#pragma unroll
    for (int qq = 0; qq < 4; ++qq) {
        float4 u = xp[qq];
        xv[qq*4+0] = u.x; xv[qq*4+1] = u.y; xv[qq*4+2] = u.z; xv[qq*4+3] = u.w;
    }
    float o[16];
#pragma unroll
    for (int j = 0; j < 16; ++j) {
        float v = slb[j];
#pragma unroll
        for (int k = 0; k < 16; ++k) v = fmaf(av[k], slw[k*16+j], v);
#pragma unroll
        for (int k = 0; k < 16; ++k) v = fmaf(xv[k], srw[k*16+j], v);
        o[j] = v > 0.f ? v : 0.f;
    }
    float4* op = reinterpret_cast<float4*>(X + (size_t)node * 16);
#pragma unroll
    for (int qq = 0; qq < 4; ++qq)
        op[qq] = make_float4(o[qq*4+0], o[qq*4+1], o[qq*4+2], o[qq*4+3]);
    float gg = 0.f;
#pragma unroll
    for (int j = 0; j < 16; ++j) {
        float u = sp3b[j];
#pragma unroll
        for (int k = 0; k < 16; ++k) u = fmaf(o[k], sp3w[k*16+j], u);
        u = u > 0.f ? u : 0.f;
        gg = fmaf(u, sl3w[j], gg);
    }
    g[node] = gg;
}

__global__ __launch_bounds__(256) void layer3_kernel(
    const int* __restrict__ counts, const unsigned int* __restrict__ sorted,
    const float* __restrict__ g, const float* __restrict__ X,
    const float* __restrict__ l3b, const float* __restrict__ r3w,
    float* __restrict__ out)
{
    __shared__ float acc[256];
    __shared__ float srw[16];
    __shared__ float sb;
    int t = threadIdx.x, b = blockIdx.x;
    acc[t] = 0.f;
    if (t < 16) srw[t] = r3w[t];
    if (t == 0) sb = l3b[0];
    __syncthreads();
    int beg = counts[b * NBP];
    int end = (b == K_B - 1) ? NE : counts[(b + 1) * NBP];
    for (int e = beg + t; e < end; e += 256) {
        unsigned v = sorted[e];
        int s = v & 0xFFFFF;
        int dlo = v >> 20;
        atomicAdd(&acc[dlo], g[s]);
    }
    __syncthreads();
    int node = (b << 8) + t;
    if (node >= NN) return;
    float val = acc[t] + sb;
    const float4* xp = reinterpret_cast<const float4*>(X + (size_t)node * 16);
#pragma unroll
    for (int qq = 0; qq < 4; ++qq) {
        float4 u = xp[qq];
        val = fmaf(u.x, srw[qq*4+0], val);
        val = fmaf(u.y, srw[qq*4+1], val);
        val = fmaf(u.z, srw[qq*4+2], val);
        val = fmaf(u.w, srw[qq*4+3], val);
    }
    out[node] = 1.f / (1.f + expf(-val));
}

// ================= launch =================

extern "C" void kernel_launch(void* const* d_in, const int* in_sizes, int n_in,
                              void* d_out, int out_size, void* d_ws, size_t ws_size,
                              hipStream_t stream) {
    const float* x   = (const float*)d_in[0];
    const int*   ei  = (const int*)d_in[1];
    const float* p1w = (const float*)d_in[2];
    const float* p1b = (const float*)d_in[3];
    const float* l1w = (const float*)d_in[4];
    const float* l1b = (const float*)d_in[5];
    const float* r1w = (const float*)d_in[6];
    const float* p2w = (const float*)d_in[7];
    const float* p2b = (const float*)d_in[8];
    const float* l2w = (const float*)d_in[9];
    const float* l2b = (const float*)d_in[10];
    const float* r2w = (const float*)d_in[11];
    const float* p3w = (const float*)d_in[12];
    const float* p3b = (const float*)d_in[13];
    const float* l3w = (const float*)d_in[14];
    const float* l3b = (const float*)d_in[15];
    const float* r3w = (const float*)d_in[16];
    float* out = (float*)d_out;

    char* ws = (char*)d_ws;
    // exact byte layout (proven ws >= 96,000,000 B from round 1)
    float*        X      = (float*)(ws);                  // 32,000,000  x2 then x3 in place
    float*        H2     = (float*)(ws + 32000000);       // 32,000,000  h2
    unsigned int* sorted = (unsigned int*)(ws + 64000000);// 20,000,000  packed edges
    float4*       h1     = (float4*)(ws + 84000000);      //  8,000,000  h1 (padded rows)
    float*        g      = (float*)(ws + 84000000);       //  2,000,000  g (reuses dead h1)
    int*          counts = (int*)(ws + 92000000);         //  3,915,776  (M_PAD ints)
    int*          partial= (int*)(ws + 95915776);         //  956

    const int nbN = (NN + 255) / 256;   // 1954

    // ---- radix partition: edges -> dst-bucket-contiguous, zero global atomics ----
    hipMemsetAsync(counts, 0, (size_t)M_PAD * sizeof(int), stream);
    pass1_count<<<NBP, 256, 0, stream>>>(ei, counts);
    scan_reduce<<<NB_SC, 256, 0, stream>>>(counts, partial);
    scan_mid<<<1, 256, 0, stream>>>(partial);
    scan_apply<<<NB_SC, 256, 0, stream>>>(counts, partial);
    pass2_scatter<<<NBP, 256, 0, stream>>>(ei, counts, sorted);

    // ---- layers (one block per bucket; LDS accumulate; fused epilogues) ----
    proj1<<<nbN, 256, 0, stream>>>(x, p1w, p1b, h1);
    layer1_kernel<<<K_B, 256, 0, stream>>>(counts, sorted, h1, x,
                                           l1w, l1b, r1w, p2w, p2b, X, H2);
    layer2_kernel<<<K_B, 256, 0, stream>>>(counts, sorted, H2, X,
                                           l2w, l2b, r2w, p3w, p3b, l3w, g);
    layer3_kernel<<<K_B, 256, 0, stream>>>(counts, sorted, g, X, l3b, r3w, out);
}